// Round 12
// baseline (20627.565 us; speedup 1.0000x reference)
//
#include <hip/hip_runtime.h>
#include <math.h>

#define NDIM 4096
#define NR   4095        // rounds = N-1 (rotating positions)
#define NPAIRS 2048      // N/2 tables
#define CB   2           // columns per WAVE (block covers 4 waves * 2 = 8)
#define NTHREADS 256
#define TPT  32          // tables per LANE; each wave owns the FULL ring

// Precompute (c, s) per (round, table); bake in the orientation sign:
// table k at round r holds players a=(r+k)%NR (top) and b=(r-k)%NR (bottom,
// or 4095 fixed for k=0). Reference rotates (i,j)=(min,max) with
// U[i]=c*Ui-s*Uj, U[j]=s*Ui+c*Uj. If top==j negate s. top>bottom iff 0<k<=r<NR-k.
__global__ void cs_precompute(const float* __restrict__ thetas,
                              const int* __restrict__ round_theta,
                              float2* __restrict__ cs, int total) {
    int idx = blockIdx.x * blockDim.x + threadIdx.x;
    if (idx >= total) return;
    int r = idx / NPAIRS;
    int k = idx - r * NPAIRS;
    float th = thetas[round_theta[idx]];
    float s, c;
    sincosf(th, &s, &c);
    if (k > 0 && k <= r && r < NR - k) s = -s;
    cs[idx] = make_float2(c, s);
}

// WAVE-PRIVATE RING (r11/r12). History: r0-r10 partitioned the ring across
// 4 waves -> block barrier every round; ~2.1ms of 4.8ms was barrier
// coupling (r10: removing the vmcnt drain alone was neutral). Now each
// wave owns the whole ring (TPT=32/lane) over CB=2 columns: exchange =
// intra-wave shfl only. NO LDS, NO __syncthreads. Phase-rename mod 32,
// 8 rounds unrolled, rotate-by-8 register permutation every 8 rounds.
// cs: two half-round float4x8 buffers X,Y. r12 ordering: X(r+1) loaded
// right after u=15 frees X; Y(r+1) loaded after u=31 frees Y -> only one
// 32-reg load group in flight at a time (peak pressure), ~half-round
// latency cover for both. (r11's round-top Y load had 64 regs in flight
// at the boundary and only ~150cy cover.)
// PIN rules (r7/r8/r9): input-only "v" pins on T/B each phase MANDATORY
// (SROA + VGPR residence + schedule fence), zero cost; never cap launch
// bounds below live-set (r9: spill disaster); tied "+v" costs ~1 mov/
// operand/phase (r3-r6).
#define PIN8(A, U)                                                      \
    asm volatile("" :: "v"(A[(U)][0]),   "v"(A[(U)][1]),                \
                       "v"(A[(U)+1][0]), "v"(A[(U)+1][1]),              \
                       "v"(A[(U)+2][0]), "v"(A[(U)+2][1]),              \
                       "v"(A[(U)+3][0]), "v"(A[(U)+3][1]))

#define PINALL()                                                        \
  { PIN8(T, 0);  PIN8(T, 4);  PIN8(T, 8);  PIN8(T, 12);                 \
    PIN8(T, 16); PIN8(T, 20); PIN8(T, 24); PIN8(T, 28);                 \
    PIN8(B, 0);  PIN8(B, 4);  PIN8(B, 8);  PIN8(B, 12);                 \
    PIN8(B, 16); PIN8(B, 20); PIN8(B, 24); PIN8(B, 28); }

// One round at compile-time phase P. top[u] lives in T[(u+P)&31],
// bottom[u] in B[(u-P+32)&31]. DO_PF: prefetch X,Y <- round RND+1.
#define ROUND(P, RND, DO_PF)                                                  \
  {                                                                           \
    PINALL();                                                                 \
    float na0[CB], nb0[CB], nbL[CB], tt[CB], bi[CB];                          \
    { /* u=0: na exported left (shfl), nb deferred (lane0 turnaround) */      \
      const float c_ = X[0].x, s_ = X[0].y;                                   \
      _Pragma("unroll") for (int c = 0; c < CB; ++c) {                        \
        float a = T[(P) & 31][c], b = B[(32 - (P)) & 31][c];                  \
        na0[c] = fmaf(c_, a, -(s_ * b));                                      \
        nb0[c] = fmaf(s_, a, c_ * b); } }                                     \
    _Pragma("unroll") for (int c = 0; c < CB; ++c)                            \
      tt[c] = __shfl_down(na0[c], 1);     /* early: latency hidden */         \
    _Pragma("unroll") for (int u = 1; u <= 15; ++u) {                         \
      const float c_ = (u & 1) ? X[u >> 1].z : X[u >> 1].x;                   \
      const float s_ = (u & 1) ? X[u >> 1].w : X[u >> 1].y;                   \
      _Pragma("unroll") for (int c = 0; c < CB; ++c) {                        \
        float a = T[(u + (P)) & 31][c], b = B[(u - (P) + 32) & 31][c];        \
        T[(u + (P)) & 31][c] = fmaf(c_, a, -(s_ * b));                        \
        B[(u - (P) + 32) & 31][c] = fmaf(s_, a, c_ * b); } }                  \
    if (DO_PF) { /* X freed after u=15: load round RND+1 first half */        \
      const float4* px_ = cs4 + (size_t)((RND) + 1) * 1024 + base;            \
      _Pragma("unroll") for (int j = 0; j < 8; ++j) X[j] = px_[j]; }          \
    _Pragma("unroll") for (int u = 16; u <= 30; ++u) {                        \
      const float c_ = (u & 1) ? Y[(u - 16) >> 1].z : Y[(u - 16) >> 1].x;     \
      const float s_ = (u & 1) ? Y[(u - 16) >> 1].w : Y[(u - 16) >> 1].y;     \
      _Pragma("unroll") for (int c = 0; c < CB; ++c) {                        \
        float a = T[(u + (P)) & 31][c], b = B[(u - (P) + 32) & 31][c];        \
        T[(u + (P)) & 31][c] = fmaf(c_, a, -(s_ * b));                        \
        B[(u - (P) + 32) & 31][c] = fmaf(s_, a, c_ * b); } }                  \
    { /* u=31: na in place, nb exported right (lane63 wraps to own top) */    \
      const float c_ = Y[7].z, s_ = Y[7].w;                                   \
      _Pragma("unroll") for (int c = 0; c < CB; ++c) {                        \
        float a = T[(31 + (P)) & 31][c], b = B[(31 - (P) + 32) & 31][c];      \
        T[(31 + (P)) & 31][c] = fmaf(c_, a, -(s_ * b));                       \
        nbL[c] = fmaf(s_, a, c_ * b); } }                                     \
    if (DO_PF) { /* Y freed after u=31: load round RND+1 second half */       \
      const float4* py_ = cs4 + (size_t)((RND) + 1) * 1024 + base;            \
      _Pragma("unroll") for (int j = 0; j < 8; ++j) Y[j] = py_[8 + j]; }      \
    _Pragma("unroll") for (int c = 0; c < CB; ++c)                            \
      bi[c] = __shfl_up(nbL[c], 1);                                           \
    _Pragma("unroll") for (int c = 0; c < CB; ++c) {                          \
      T[(P) & 31][c]        = lane63 ? nbL[c] : tt[c]; /* table31 new top */  \
      B[(32 - (P)) & 31][c] = lane0 ? na0[c] : nb0[c]; /* table1 new bot */   \
      B[(63 - (P)) & 31][c] = lane0 ? nb0[c] : bi[c];  /* table0 new bot */   \
    }                                                                         \
  }

// Restore invariant after 8 rounds: T'[u]=T[(u+8)&31], B'[u]=B[(u+24)&31].
#define ROT8()                                                                \
  { _Pragma("unroll") for (int v = 0; v < 8; ++v) {                           \
      _Pragma("unroll") for (int c = 0; c < CB; ++c) {                        \
        float t0 = T[v][c];                                                   \
        T[v][c] = T[v + 8][c]; T[v + 8][c] = T[v + 16][c];                    \
        T[v + 16][c] = T[v + 24][c]; T[v + 24][c] = t0;                       \
        float b0 = B[v][c];                                                   \
        B[v][c] = B[v + 24][c]; B[v + 24][c] = B[v + 16][c];                  \
        B[v + 16][c] = B[v + 8][c]; B[v + 8][c] = b0; } } }

__global__ __launch_bounds__(NTHREADS, 2)
void rotmat_wavering(const float2* __restrict__ cs,
                     float* __restrict__ out) {
    const int tid  = threadIdx.x;
    const int lane = tid & 63;
    const int wave = tid >> 6;
    const int col0 = blockIdx.x * (4 * CB) + wave * CB;
    const bool lane0  = (lane == 0);
    const bool lane63 = (lane == 63);

    float T[TPT][CB], B[TPT][CB];
    // phase 0: top[u] -> T[u] (row g = lane*32+u), bottom[u] -> B[u] (row 4095-g)
#pragma unroll
    for (int u = 0; u < TPT; ++u) {
        int g = lane * TPT + u;
        int rowB = NR - g;            // g=0 -> 4095 (fixed player)
#pragma unroll
        for (int c = 0; c < CB; ++c) {
            T[u][c] = (g == col0 + c) ? 1.f : 0.f;
            B[u][c] = (rowB == col0 + c) ? 1.f : 0.f;
        }
    }

    // cs as float4: round r occupies 1024 float4; lane covers 16 of them.
    const float4* cs4 = (const float4*)cs;
    const int base = lane * 16;
    float4 X[8], Y[8];
    { const float4* p = cs4 + base;     // round 0, both halves
#pragma unroll
      for (int j = 0; j < 8; ++j) X[j] = p[j];
#pragma unroll
      for (int j = 0; j < 8; ++j) Y[j] = p[8 + j]; }

    int r = 0;
    for (int it = 0; it < 511; ++it, r += 8) {   // rounds 0..4087
        ROUND(0, r,     1)
        ROUND(1, r + 1, 1)
        ROUND(2, r + 2, 1)
        ROUND(3, r + 3, 1)
        ROUND(4, r + 4, 1)
        ROUND(5, r + 5, 1)
        ROUND(6, r + 6, 1)
        ROUND(7, r + 7, 1)
        ROT8();
    }
    // tail: rounds 4088..4094 (phases 0..6); last prefetch targets 4094
    ROUND(0, r,     1)
    ROUND(1, r + 1, 1)
    ROUND(2, r + 2, 1)
    ROUND(3, r + 3, 1)
    ROUND(4, r + 4, 1)
    ROUND(5, r + 5, 1)
    ROUND(6, r + 6, 0)

    // final shift = 4095 - 511*8 = 7: top[u] at T[(u+7)&31],
    // bottom[u] at B[(u-7+32)&31] = B[(u+25)&31].
#pragma unroll
    for (int u = 0; u < TPT; ++u) {
        int g = lane * TPT + u;
        int rb = NR - g;
        float* Tp = T[(u + 7) & 31];
        float* Bp = B[(u + 25) & 31];
        *(float2*)&out[(size_t)g * NDIM + col0] = make_float2(Tp[0], Tp[1]);
        *(float2*)&out[(size_t)rb * NDIM + col0] = make_float2(Bp[0], Bp[1]);
    }
}

extern "C" void kernel_launch(void* const* d_in, const int* in_sizes, int n_in,
                              void* d_out, int out_size, void* d_ws, size_t ws_size,
                              hipStream_t stream) {
    const float* thetas      = (const float*)d_in[0];
    const int*   round_theta = (const int*)d_in[3];
    float*       out         = (float*)d_out;

    const int total = NR * NPAIRS;
    float2* cs = (float2*)d_ws;   // 67 MB workspace (verified sufficient)

    cs_precompute<<<(total + 255) / 256, 256, 0, stream>>>(
        thetas, round_theta, cs, total);
    rotmat_wavering<<<NDIM / (4 * CB), NTHREADS, 0, stream>>>(cs, out);
}

// Round 13
// 9706.434 us; speedup vs baseline: 2.1251x; 2.1251x over previous
//
#include <hip/hip_runtime.h>
#include <math.h>

#define NDIM 4096
#define NR   4095        // rounds = N-1 (rotating positions)
#define NPAIRS 2048      // N/2 tables
#define CB   4           // columns per block
#define NTHREADS 128     // 2 waves per block; grid = 1024 blocks
#define NWAVES (NTHREADS / 64)   // 2
#define TPT  16          // tables per thread (NPAIRS / NTHREADS)

// Precompute (c, s) per (round, table); bake in the orientation sign:
// table k at round r holds players a=(r+k)%NR (top) and b=(r-k)%NR (bottom,
// or 4095 fixed for k=0). Reference rotates (i,j)=(min,max) with
// U[i]=c*Ui-s*Uj, U[j]=s*Ui+c*Uj. If top==j negate s. top>bottom iff 0<k<=r<NR-k.
__global__ void cs_precompute(const float* __restrict__ thetas,
                              const int* __restrict__ round_theta,
                              float2* __restrict__ cs, int total) {
    int idx = blockIdx.x * blockDim.x + threadIdx.x;
    if (idx >= total) return;
    int r = idx / NPAIRS;
    int k = idx - r * NPAIRS;
    float th = thetas[round_theta[idx]];
    float s, c;
    sincosf(th, &s, &c);
    if (k > 0 && k <= r && r < NR - k) s = -s;
    cs[idx] = make_float2(c, s);
}

// 2-WAVE RING (r13). History: 4-wave block ring (r8/r10, 4104us bench) is
// VALU ~2.7ms + barrier-coupling stall ~2.1ms (r10 proved the stall is NOT
// the vmcnt drain). 1-wave ring (r12) spilled: per-lane cs = full ring =
// 64 regs on top of T/B. Midpoint: 2 waves per ring, TPT=16, CB=4,
// NTHREADS=128, grid 1024 -> 4 blocks/CU (4 independent barrier streams,
// 2-wave coupling), state = T/B 128 + X 32 + temps ~185 < 256 budget.
// Phase-rename mod 16, 16 phases per outer iteration, no rotate needed.
// cs: SINGLE buffer X[8] (float4); X[0..3] reloaded with next round's
// first half right after u=7 frees it, X[4..7] after u=15 -> one 16-reg
// load group in flight, ~130cy FMA cover each, rest hidden by TLP.
// PIN rules (r7/r8/r9/r12): input-only "v" pins on T/B each phase are
// MANDATORY (SROA + VGPR residence + schedule fence), zero copy tax;
// never cap launch bounds below live-set; tied "+v" costs ~1 mov/op/phase.
// XBAR (r10, neutral-safe): lgkmcnt-only barrier keeps the cs prefetch
// in flight across the round boundary (vmcnt(0) would drain it).
#define XBAR()                                                          \
  { asm volatile("s_waitcnt lgkmcnt(0)" ::: "memory");                  \
    __builtin_amdgcn_s_barrier(); }

#define PIN16(A, U)                                                    \
    asm volatile("" :: "v"(A[(U)][0]),   "v"(A[(U)][1]),               \
                       "v"(A[(U)][2]),   "v"(A[(U)][3]),               \
                       "v"(A[(U)+1][0]), "v"(A[(U)+1][1]),             \
                       "v"(A[(U)+1][2]), "v"(A[(U)+1][3]),             \
                       "v"(A[(U)+2][0]), "v"(A[(U)+2][1]),             \
                       "v"(A[(U)+2][2]), "v"(A[(U)+2][3]),             \
                       "v"(A[(U)+3][0]), "v"(A[(U)+3][1]),             \
                       "v"(A[(U)+3][2]), "v"(A[(U)+3][3]))

#define PINALL()                                                       \
  { PIN16(T, 0); PIN16(T, 4); PIN16(T, 8); PIN16(T, 12);               \
    PIN16(B, 0); PIN16(B, 4); PIN16(B, 8); PIN16(B, 12); }

// In-place rotation of table u at phase P. top[u] in T[(u+P)&15],
// bot[u] in B[(u-P+16)&15]. cs for table u: X[u>>1] (.xy even, .zw odd).
#define UPD(U, P)                                                             \
  { const float c_ = ((U) & 1) ? X[(U) >> 1].z : X[(U) >> 1].x;               \
    const float s_ = ((U) & 1) ? X[(U) >> 1].w : X[(U) >> 1].y;               \
    _Pragma("unroll") for (int c = 0; c < CB; ++c) {                          \
      float a = T[((U) + (P)) & 15][c], b = B[((U) - (P) + 16) & 15][c];      \
      T[((U) + (P)) & 15][c] = fmaf(c_, a, -(s_ * b));                        \
      B[((U) - (P) + 16) & 15][c] = fmaf(s_, a, c_ * b); } }

// One round at compile-time phase P. DO_PF: prefetch round RND+1 into X.
#define PHASE(P, RND, DO_PF)                                                  \
  {                                                                           \
    PINALL();                                                                 \
    float na0[CB], nb0[CB], nbL[CB], t7[CB], bi[CB];                          \
    { /* u=0: na exported left (shfl), nb deferred (tid==0 turnaround) */     \
      const float c_ = X[0].x, s_ = X[0].y;                                   \
      _Pragma("unroll") for (int c = 0; c < CB; ++c) {                        \
        float a = T[(P) & 15][c], b = B[(16 - (P)) & 15][c];                  \
        na0[c] = fmaf(c_, a, -(s_ * b));                                      \
        nb0[c] = fmaf(s_, a, c_ * b); } }                                     \
    _Pragma("unroll") for (int c = 0; c < CB; ++c)                            \
      t7[c] = __shfl_down(na0[c], 1);     /* early: latency hidden */         \
    UPD(1, P) UPD(2, P) UPD(3, P) UPD(4, P)                                   \
    UPD(5, P) UPD(6, P) UPD(7, P)                                             \
    if (DO_PF) { /* X[0..3] freed after u=7: next round first half */         \
      const float4* pf_ = csp + (size_t)((RND) + 1) * 1024;                   \
      X[0] = pf_[0]; X[1] = pf_[1]; X[2] = pf_[2]; X[3] = pf_[3];             \
    }                                                                         \
    UPD(8, P) UPD(9, P) UPD(10, P) UPD(11, P)                                 \
    UPD(12, P) UPD(13, P) UPD(14, P)                                          \
    { /* u=15: na in place, nb exported right */                              \
      const float c_ = X[7].z, s_ = X[7].w;                                   \
      _Pragma("unroll") for (int c = 0; c < CB; ++c) {                        \
        float a = T[(15 + (P)) & 15][c], b = B[(15 - (P) + 16) & 15][c];      \
        T[(15 + (P)) & 15][c] = fmaf(c_, a, -(s_ * b));                       \
        nbL[c] = fmaf(s_, a, c_ * b); } }                                     \
    if (DO_PF) { /* X[4..7] freed after u=15: next round second half */       \
      const float4* pf_ = csp + (size_t)((RND) + 1) * 1024;                   \
      X[4] = pf_[4]; X[5] = pf_[5]; X[6] = pf_[6]; X[7] = pf_[7];             \
    }                                                                         \
    _Pragma("unroll") for (int c = 0; c < CB; ++c)                            \
      bi[c] = __shfl_up(nbL[c], 1);                                           \
    if (lane == 0) { _Pragma("unroll") for (int c = 0; c < CB; ++c)           \
        naBuf[(P) & 1][wave][c] = na0[c]; }                                   \
    if (lane == 63) { _Pragma("unroll") for (int c = 0; c < CB; ++c)          \
        nbBuf[(P) & 1][wave][c] = nbL[c]; }                                   \
    XBAR();                                                                   \
    if (lane == 63) {                                                         \
      if (wave < NWAVES - 1) { _Pragma("unroll")                              \
        for (int c = 0; c < CB; ++c) t7[c] = naBuf[(P) & 1][wave + 1][c]; }   \
      else { _Pragma("unroll")                                                \
        for (int c = 0; c < CB; ++c) t7[c] = nbL[c]; } }                      \
    if (lane == 0 && wave > 0) { _Pragma("unroll")                            \
      for (int c = 0; c < CB; ++c) bi[c] = nbBuf[(P) & 1][wave - 1][c]; }     \
    _Pragma("unroll") for (int c = 0; c < CB; ++c) {                          \
      T[(P) & 15][c] = t7[c];                        /* top import slot */    \
      B[(16 - (P)) & 15][c]      = (tid == 0) ? na0[c] : nb0[c];              \
      B[(15 - (P) + 16) & 15][c] = (tid == 0) ? nb0[c] : bi[c];               \
    }                                                                         \
  }

__global__ __launch_bounds__(NTHREADS, 2)
void rotmat_systolic(const float2* __restrict__ cs,
                     float* __restrict__ out) {
    __shared__ float naBuf[2][NWAVES][CB];
    __shared__ float nbBuf[2][NWAVES][CB];

    const int tid  = threadIdx.x;
    const int lane = tid & 63;
    const int wave = tid >> 6;
    const int col0 = blockIdx.x * CB;

    float T[TPT][CB], B[TPT][CB];
    // phase 0: top[u] -> T[u] (row g = tid*16+u), bot[u] -> B[u] (row 4095-g)
#pragma unroll
    for (int u = 0; u < TPT; ++u) {
        int g = tid * TPT + u;
        int rowB = NR - g;            // g=0 -> 4095 (fixed player)
#pragma unroll
        for (int c = 0; c < CB; ++c) {
            T[u][c] = (g == col0 + c) ? 1.f : 0.f;
            B[u][c] = (rowB == col0 + c) ? 1.f : 0.f;
        }
    }

    // cs as float4: round r occupies 1024 float4; thread's 8 quads at
    // r*1024 + tid*8 + j (tables tid*16 + 2j, 2j+1).
    const float4* csp = (const float4*)cs + (size_t)tid * (TPT / 2);
    float4 X[8];
#pragma unroll
    for (int j = 0; j < 8; ++j) X[j] = csp[j];    // round 0

    int r = 0;
    for (int it = 0; it < 255; ++it, r += 16) {   // rounds 0..4079
        PHASE(0,  r,      1)
        PHASE(1,  r + 1,  1)
        PHASE(2,  r + 2,  1)
        PHASE(3,  r + 3,  1)
        PHASE(4,  r + 4,  1)
        PHASE(5,  r + 5,  1)
        PHASE(6,  r + 6,  1)
        PHASE(7,  r + 7,  1)
        PHASE(8,  r + 8,  1)
        PHASE(9,  r + 9,  1)
        PHASE(10, r + 10, 1)
        PHASE(11, r + 11, 1)
        PHASE(12, r + 12, 1)
        PHASE(13, r + 13, 1)
        PHASE(14, r + 14, 1)
        PHASE(15, r + 15, 1)
    }
    // tail: rounds 4080..4094 (phases 0..14); last prefetch targets 4094
    PHASE(0,  r,      1)
    PHASE(1,  r + 1,  1)
    PHASE(2,  r + 2,  1)
    PHASE(3,  r + 3,  1)
    PHASE(4,  r + 4,  1)
    PHASE(5,  r + 5,  1)
    PHASE(6,  r + 6,  1)
    PHASE(7,  r + 7,  1)
    PHASE(8,  r + 8,  1)
    PHASE(9,  r + 9,  1)
    PHASE(10, r + 10, 1)
    PHASE(11, r + 11, 1)
    PHASE(12, r + 12, 1)
    PHASE(13, r + 13, 1)
    PHASE(14, r + 14, 0)

    // final shift Q = 4095 mod 16 = 15: top[u] at T[(u+15)&15],
    // bot[u] at B[(u-15+16)&15] = B[(u+1)&15].
#pragma unroll
    for (int u = 0; u < TPT; ++u) {
        int g = tid * TPT + u;
        int rb = NR - g;
        float* Tp = T[(u + 15) & 15];
        float* Bp = B[(u + 1) & 15];
        *(float4*)&out[(size_t)g * NDIM + col0] =
            make_float4(Tp[0], Tp[1], Tp[2], Tp[3]);
        *(float4*)&out[(size_t)rb * NDIM + col0] =
            make_float4(Bp[0], Bp[1], Bp[2], Bp[3]);
    }
}

extern "C" void kernel_launch(void* const* d_in, const int* in_sizes, int n_in,
                              void* d_out, int out_size, void* d_ws, size_t ws_size,
                              hipStream_t stream) {
    const float* thetas      = (const float*)d_in[0];
    const int*   round_theta = (const int*)d_in[3];
    float*       out         = (float*)d_out;

    const int total = NR * NPAIRS;
    float2* cs = (float2*)d_ws;   // 67 MB workspace (verified sufficient)

    cs_precompute<<<(total + 255) / 256, 256, 0, stream>>>(
        thetas, round_theta, cs, total);
    rotmat_systolic<<<NDIM / CB, NTHREADS, 0, stream>>>(cs, out);
}